// Round 10
// baseline (174.264 us; speedup 1.0000x reference)
//
#include <hip/hip_runtime.h>

#define N_NODES 50000
#define N_EDGES 1600000
#define NB 782            // buckets of 64 dst nodes: ceil(50000/64)
#define NBB 256           // binning blocks
#define CHUNK 6250        // N_EDGES / NBB (exact, even)
#define CAP 2560          // fixed bucket capacity (mean 2046 + 11 sigma)
#define SCAP 3072         // srcp per-bucket capacity (CAP + pad slack)
#define ZROW 50000        // dummy src row (all zeros) for padding
#define NTILES 3125       // 50000 / 16 exact

typedef unsigned short ushort_t;
typedef _Float16 v8h __attribute__((ext_vector_type(8)));
typedef _Float16 v4h __attribute__((ext_vector_type(4)));
typedef float f32x4_t __attribute__((ext_vector_type(4)));

__device__ __forceinline__ int rlanei(int v, int l) {
  return __builtin_amdgcn_readlane(v, l);
}
__device__ __forceinline__ float rlanef(float v, int l) {
  return __int_as_float(__builtin_amdgcn_readlane(__float_as_int(v), l));
}

// ========== fused binning + weight prep (independent block families) ======
// Blocks 0..255: r8-proven binning (pack into LDS, reserve, scatter).
// Blocks 256..263: weight compose/pack (LDS-staged, stride-65).
// gcur is pre-zeroed by hipMemsetAsync.
__global__ __launch_bounds__(256) void k_binw(
    const int* __restrict__ ei, int* __restrict__ gcur, int* __restrict__ bins,
    const float* __restrict__ Wz, const float* __restrict__ bz,
    const float* __restrict__ Wlz, const float* __restrict__ blz,
    const float* __restrict__ Wh, const float* __restrict__ bh,
    const float* __restrict__ Wlh, const float* __restrict__ blh,
    const float* __restrict__ Wout, float* __restrict__ B2f,
    _Float16* __restrict__ Bzh, _Float16* __restrict__ Bwo) {
  __shared__ int arena[8320];   // bin: 2*NB+CHUNK=7814; wprep: 2*4160=8320
  int tid = threadIdx.x, blk = blockIdx.x;
  if (blk < NBB) {
    int* h    = arena;          // 782
    int* segb = arena + NB;     // 782
    int* pk   = arena + 2 * NB; // 6250
    for (int i = tid; i < NB; i += 256) h[i] = 0;
    __syncthreads();
    const int2* s2 = (const int2*)(ei + blk * CHUNK);
    const int2* d2 = (const int2*)(ei + N_EDGES + blk * CHUNK);
    for (int i = tid; i < CHUNK / 2; i += 256) {
      int2 s = s2[i];
      int2 d = d2[i];
      pk[2 * i]     = s.x | ((d.x & 63) << 16) | ((d.x >> 6) << 22);
      pk[2 * i + 1] = s.y | ((d.y & 63) << 16) | ((d.y >> 6) << 22);
      atomicAdd(&h[d.x >> 6], 1);
      atomicAdd(&h[d.y >> 6], 1);
    }
    __syncthreads();
    for (int b = tid; b < NB; b += 256) {
      int c = h[b];
      segb[b] = c ? atomicAdd(&gcur[b], c) : 0;
      h[b] = 0;                       // reuse as local cursor
    }
    __syncthreads();
    for (int i = tid; i < CHUNK; i += 256) {
      int v = pk[i];
      int b = (unsigned)v >> 22;
      int p = atomicAdd(&h[b], 1);
      bins[b * CAP + segb[b] + p] = v & 0x3FFFFF;   // src | dl<<16
    }
  } else {
    // weight prep: wblk 0-3 z-path, 4-7 h-path; ntile = wblk&3
    int wblk = blk - NBB;
    float* A  = (float*)arena;           // 64x65
    float* Bm = (float*)(arena + 4160);  // 64x65
    bool zpath = wblk < 4;
    const float* Wsrc = zpath ? Wz : Wh;
    const float* Lsrc = zpath ? Wlz : Wlh;
    for (int idx = tid; idx < 4096; idx += 256) {
      A[(idx >> 6) * 65 + (idx & 63)] = Wsrc[idx];
      Bm[(idx >> 6) * 65 + (idx & 63)] = Lsrc[idx];
    }
    __syncthreads();
    // Bzh[t]: lane=(t>>3)&63, j=t&7, ntile=t>>10, ks=(t>>9)&1;
    // n=ntile*16+(lane&15), k=ks*32+((lane>>4)<<3)+j  (verified r6-r9)
    int lane = (tid >> 1) & 63;
    int j0 = (tid & 1) * 4;
    int ks = (tid >> 7) & 1;
    int k0 = ks * 32 + ((lane >> 4) << 3) + j0;
    int col = (wblk & 3) * 16 + (lane & 15);
    float a0 = 0.f, a1 = 0.f, a2 = 0.f, a3 = 0.f;
    for (int q = 0; q < 64; ++q) {
      float bv = Bm[q * 65 + col];
      a0 = fmaf(A[k0 * 65 + q], bv, a0);
      a1 = fmaf(A[(k0 + 1) * 65 + q], bv, a1);
      a2 = fmaf(A[(k0 + 2) * 65 + q], bv, a2);
      a3 = fmaf(A[(k0 + 3) * 65 + q], bv, a3);
    }
    int tb = wblk * 1024 + tid * 4;
    v4h o; o[0] = (_Float16)a0; o[1] = (_Float16)a1;
    o[2] = (_Float16)a2; o[3] = (_Float16)a3;
    *(v4h*)(Bzh + tb) = o;
    if ((wblk == 0 || wblk == 4) && tid < 64) {
      float v = zpath ? blz[tid] : blh[tid];
      const float* bb = zpath ? bz : bh;
      for (int q = 0; q < 64; ++q) v = fmaf(bb[q], Bm[q * 65 + tid], v);
      B2f[tid * 2 + (zpath ? 0 : 1)] = v;
    }
    if (wblk == 1) {
      for (int e2 = 0; e2 < 12; ++e2) {
        int t2 = tid * 12 + e2;
        int ln = (t2 >> 3) & 63, j = t2 & 7;
        int ntile = t2 >> 10, ks2 = (t2 >> 9) & 1;
        int n = ntile * 16 + (ln & 15);
        int k = ks2 * 32 + ((ln >> 4) << 3) + j;
        Bwo[t2] = (_Float16)((n < 45) ? Wout[k * 45 + n] : 0.f);
      }
    }
  }
}

// ---------------- per-bucket sort -> padded per-node CSR + dinv + xp ------
__global__ __launch_bounds__(256, 4) void k_sort(
    const int* __restrict__ bins, const int* __restrict__ gcur,
    const float* __restrict__ x,
    ushort_t* __restrict__ srcp, int2* __restrict__ rowiv,
    float* __restrict__ dinv, _Float16* __restrict__ xp) {
  __shared__ int dg[64], lo[64], cur[64];
  __shared__ float sdin[64];
  __shared__ int Tsh;
  __shared__ ushort_t buf[3072];   // max T = count + 64*7 < 3072
  int tid = threadIdx.x, b = blockIdx.x;
  int start = b * CAP, end = start + gcur[b];
  if (tid < 64) dg[tid] = 0;
  __syncthreads();
  for (int i = start + tid; i < end; i += 256)
    atomicAdd(&dg[bins[i] >> 16], 1);
  __syncthreads();
  int pdv = 0;
  if (tid < 64) { pdv = (dg[tid] + 7) & ~7; lo[tid] = pdv; }
  __syncthreads();
  for (int off = 1; off < 64; off <<= 1) {
    int u = 0;
    if (tid < 64 && tid >= off) u = lo[tid - off];
    __syncthreads();
    if (tid < 64) lo[tid] += u;
    __syncthreads();
  }
  int ex = 0;
  if (tid < 64) {
    ex = lo[tid] - pdv;       // exclusive padded offset
    cur[tid] = ex;
    if (tid == 63) Tsh = lo[63];
  }
  __syncthreads();
  int T = Tsh;
  int base = b * SCAP;        // fixed per-bucket srcp region
  for (int i = tid; i < T; i += 256) buf[i] = (ushort_t)ZROW;
  __syncthreads();
  for (int i = start + tid; i < end; i += 256) {
    int v = bins[i];
    int dl = v >> 16;
    int p = atomicAdd(&cur[dl], 1);
    buf[p] = (ushort_t)(v & 0xFFFF);
  }
  __syncthreads();
  for (int i = tid; i < T; i += 256) srcp[base + i] = buf[i];
  if (tid < 64) {
    int v = b * 64 + tid;
    if (v < N_NODES) {
      rowiv[v] = make_int2(base + ex, pdv);
      float dv = rsqrtf((float)dg[tid] + 2.0f);
      dinv[v] = dv;
      sdin[tid] = dv;
    } else {
      sdin[tid] = 0.f;
    }
  }
  __syncthreads();
  int nb64 = b * 4096;  // b*64*64
  for (int idx = tid; idx < 4096; idx += 256) {
    int v = b * 64 + (idx >> 6);
    if (v < N_NODES) xp[nb64 + idx] = (_Float16)(sdin[idx >> 6] * x[nb64 + idx]);
  }
  if (b == 0 && tid < 64) xp[ZROW * 64 + tid] = (_Float16)0.f;
}

// ========== fused gather + MFMA cell + readout: one wave per 16-node tile ==
// Gather (4 edges/wave-load, 4-deep MLP) -> sx fp16 into per-wave tbuf ->
// A-frags -> z|h MFMA -> nonlinearity -> tbuf transpose -> readout MFMA.
// No barriers (tbuf is wave-private); early return for tail waves is safe.
__global__ __launch_bounds__(256) void k_gcell(
    const ushort_t* __restrict__ srcp, const int2* __restrict__ rowiv,
    const float* __restrict__ dinv, const _Float16* __restrict__ xp,
    const _Float16* __restrict__ Bzh, const _Float16* __restrict__ Bwo,
    const float2* __restrict__ B2, const float* __restrict__ bout,
    float* __restrict__ out) {
  __shared__ __align__(16) _Float16 tbuf[4][16][72];
  int tid = threadIdx.x;
  int lane = tid & 63, wv = tid >> 6;
  int tile = blockIdx.x * 4 + wv;
  if (tile >= NTILES) return;
  int l15 = lane & 15, quad = lane >> 4;
  int chOff = l15 << 2;          // channel quad offset (gather role)

  // prefetch per-node metadata for the tile (lanes 0..15)
  int rbx = 0, rby = 0; float dvv = 0.f;
  if (lane < 16) {
    int2 ri = rowiv[tile * 16 + lane];
    rbx = ri.x; rby = ri.y;
    dvv = dinv[tile * 16 + lane];
  }

  // ---- gather phase: 16 nodes ----
  for (int n = 0; n < 16; ++n) {
    int beg = rlanei(rbx, n);
    int pd  = rlanei(rby, n);    // multiple of 8
    float aA0=0.f,aA1=0.f,aA2=0.f,aA3=0.f, aB0=0.f,aB1=0.f,aB2=0.f,aB3=0.f;
    float aC0=0.f,aC1=0.f,aC2=0.f,aC3=0.f, aD0=0.f,aD1=0.f,aD2=0.f,aD3=0.f;
    for (int e = beg; e < beg + pd; e += 64) {
      int rem = beg + pd - e;
      int m = rem < 64 ? rem : 64;   // multiple of 8
      int sv = (lane < m) ? (int)srcp[e + lane] : ZROW;
      int t = 0;
      for (; t + 16 <= m; t += 16) {   // 16 edges: 4 loads in flight
        int sA = __builtin_amdgcn_ds_bpermute((t + quad) << 2, sv);
        int sB = __builtin_amdgcn_ds_bpermute((t + 4 + quad) << 2, sv);
        int sC = __builtin_amdgcn_ds_bpermute((t + 8 + quad) << 2, sv);
        int sD = __builtin_amdgcn_ds_bpermute((t + 12 + quad) << 2, sv);
        v4h rA = *(const v4h*)(xp + (sA << 6) + chOff);
        v4h rB = *(const v4h*)(xp + (sB << 6) + chOff);
        v4h rC = *(const v4h*)(xp + (sC << 6) + chOff);
        v4h rD = *(const v4h*)(xp + (sD << 6) + chOff);
        aA0 += (float)rA[0]; aA1 += (float)rA[1];
        aA2 += (float)rA[2]; aA3 += (float)rA[3];
        aB0 += (float)rB[0]; aB1 += (float)rB[1];
        aB2 += (float)rB[2]; aB3 += (float)rB[3];
        aC0 += (float)rC[0]; aC1 += (float)rC[1];
        aC2 += (float)rC[2]; aC3 += (float)rC[3];
        aD0 += (float)rD[0]; aD1 += (float)rD[1];
        aD2 += (float)rD[2]; aD3 += (float)rD[3];
      }
      if (t < m) {                    // remaining 8 edges
        int sA = __builtin_amdgcn_ds_bpermute((t + quad) << 2, sv);
        int sB = __builtin_amdgcn_ds_bpermute((t + 4 + quad) << 2, sv);
        v4h rA = *(const v4h*)(xp + (sA << 6) + chOff);
        v4h rB = *(const v4h*)(xp + (sB << 6) + chOff);
        aA0 += (float)rA[0]; aA1 += (float)rA[1];
        aA2 += (float)rA[2]; aA3 += (float)rA[3];
        aB0 += (float)rB[0]; aB1 += (float)rB[1];
        aB2 += (float)rB[2]; aB3 += (float)rB[3];
      }
    }
    float a0 = (aA0 + aB0) + (aC0 + aD0);
    float a1 = (aA1 + aB1) + (aC1 + aD1);
    float a2 = (aA2 + aB2) + (aC2 + aD2);
    float a3 = (aA3 + aB3) + (aC3 + aD3);
    a0 += __shfl_xor(a0, 16); a1 += __shfl_xor(a1, 16);
    a2 += __shfl_xor(a2, 16); a3 += __shfl_xor(a3, 16);
    a0 += __shfl_xor(a0, 32); a1 += __shfl_xor(a1, 32);
    a2 += __shfl_xor(a2, 32); a3 += __shfl_xor(a3, 32);
    if (lane < 16) {
      float dv = rlanef(dvv, n);
      v4h self = *(const v4h*)(xp + ((tile * 16 + n) << 6) + chOff);
      v4h o;
      o[0] = (_Float16)(dv * a0 + 2.f * dv * (float)self[0]);
      o[1] = (_Float16)(dv * a1 + 2.f * dv * (float)self[1]);
      o[2] = (_Float16)(dv * a2 + 2.f * dv * (float)self[2]);
      o[3] = (_Float16)(dv * a3 + 2.f * dv * (float)self[3]);
      *(v4h*)&tbuf[wv][n][chOff] = o;
    }
  }
  __asm__ volatile("s_waitcnt lgkmcnt(0)" ::: "memory");  // wave-local LDS

  // ---- A fragments from tbuf: A[m=l15][k=quad*8+j] ----
  v8h a0 = *(const v8h*)&tbuf[wv][l15][quad * 8];
  v8h a1 = *(const v8h*)&tbuf[wv][l15][32 + quad * 8];

  // ---- B fragments + fused biases ----
  v8h bzf[8][2], bwf[3][2];
  #pragma unroll
  for (int t = 0; t < 8; ++t)
    #pragma unroll
    for (int ks = 0; ks < 2; ++ks)
      bzf[t][ks] = *(const v8h*)(Bzh + (((t * 2 + ks) * 64 + lane) << 3));
  #pragma unroll
  for (int t = 0; t < 3; ++t)
    #pragma unroll
    for (int ks = 0; ks < 2; ++ks)
      bwf[t][ks] = *(const v8h*)(Bwo + (((t * 2 + ks) * 64 + lane) << 3));
  float zb[4], hb[4], ob[3];
  #pragma unroll
  for (int t = 0; t < 4; ++t) {
    float2 bb = B2[t * 16 + l15];
    zb[t] = bb.x; hb[t] = bb.y;
  }
  #pragma unroll
  for (int t = 0; t < 3; ++t) {
    int c = t * 16 + l15;
    ob[t] = (c < 45) ? bout[c] : 0.f;
  }

  // ---- z|h GEMM ----
  f32x4_t accz[8];
  #pragma unroll
  for (int t = 0; t < 8; ++t) {
    f32x4_t c4 = {0.f, 0.f, 0.f, 0.f};
    c4 = __builtin_amdgcn_mfma_f32_16x16x32_f16(a0, bzf[t][0], c4, 0, 0, 0);
    c4 = __builtin_amdgcn_mfma_f32_16x16x32_f16(a1, bzf[t][1], c4, 0, 0, 0);
    accz[t] = c4;
  }

  // ---- nonlinearity; write relu((1-Z)*tanh(h)) back to tbuf (C-layout) ----
  #pragma unroll
  for (int t = 0; t < 4; ++t) {
    #pragma unroll
    for (int r = 0; r < 4; ++r) {
      float zv = accz[t][r] + zb[t];
      float hv = accz[t + 4][r] + hb[t];
      float Z = 1.f / (1.f + __expf(-zv));
      float tt = fminf(15.f, fmaxf(-15.f, hv));
      float e2 = __expf(-2.f * tt);
      float Th = (1.f - e2) / (1.f + e2);
      tbuf[wv][quad * 4 + r][t * 16 + l15] = (_Float16)fmaxf((1.f - Z) * Th, 0.f);
    }
  }
  __asm__ volatile("s_waitcnt lgkmcnt(0)" ::: "memory");

  v8h p0 = *(const v8h*)&tbuf[wv][l15][quad * 8];
  v8h p1 = *(const v8h*)&tbuf[wv][l15][32 + quad * 8];

  // ---- readout GEMM ----
  #pragma unroll
  for (int t = 0; t < 3; ++t) {
    f32x4_t o4 = {0.f, 0.f, 0.f, 0.f};
    o4 = __builtin_amdgcn_mfma_f32_16x16x32_f16(p0, bwf[t][0], o4, 0, 0, 0);
    o4 = __builtin_amdgcn_mfma_f32_16x16x32_f16(p1, bwf[t][1], o4, 0, 0, 0);
    int c = t * 16 + l15;
    if (c < 45) {
      #pragma unroll
      for (int r = 0; r < 4; ++r)
        out[(tile * 16 + quad * 4 + r) * 45 + c] = o4[r] + ob[t];
    }
  }
}

// ---------------- launch ----------------
extern "C" void kernel_launch(void* const* d_in, const int* in_sizes, int n_in,
                              void* d_out, int out_size, void* d_ws, size_t ws_size,
                              hipStream_t stream) {
  const float* x    = (const float*)d_in[0];
  const int*   ei   = (const int*)d_in[1];
  const float* Wz   = (const float*)d_in[2];
  const float* bz   = (const float*)d_in[3];
  const float* Wlz  = (const float*)d_in[4];
  const float* blz  = (const float*)d_in[5];
  // d_in[6..9] (W_r branch) dead: H=0 => H*R=0.
  const float* Wh   = (const float*)d_in[10];
  const float* bh   = (const float*)d_in[11];
  const float* Wlh  = (const float*)d_in[12];
  const float* blh  = (const float*)d_in[13];
  const float* Wout = (const float*)d_in[14];
  const float* bout = (const float*)d_in[15];
  float* out = (float*)d_out;

  char* w = (char*)d_ws;
  int*      bins  = (int*)(w + 0);            // 782*2560*4 = 8,007,680
  int*      gcur  = (int*)(w + 8007680);      // 3,128
  ushort_t* srcp  = (ushort_t*)(w + 8010816); // 782*3072*2 = 4,804,608
  int2*     rowiv = (int2*)(w + 12815424);    // 400,000
  float*    dinv  = (float*)(w + 13215424);   // 200,000
  float2*   B2    = (float2*)(w + 13415424);  // 512
  _Float16* Bzh   = (_Float16*)(w + 13415936);// 16,384
  _Float16* Bwo   = (_Float16*)(w + 13432320);// 6,144
  _Float16* xp    = (_Float16*)(w + 13438464);// 6,400,128 -> ends ~19.8 MB

  hipMemsetAsync(gcur, 0, NB * sizeof(int), stream);
  k_binw <<<NBB + 8, 256, 0, stream>>>(ei, gcur, bins, Wz, bz, Wlz, blz,
                                       Wh, bh, Wlh, blh, Wout,
                                       (float*)B2, Bzh, Bwo);
  k_sort <<<NB, 256, 0, stream>>>(bins, gcur, x, srcp, rowiv, dinv, xp);
  k_gcell<<<NB, 256, 0, stream>>>(srcp, rowiv, dinv, xp, Bzh, Bwo, B2,
                                  bout, out);
}

// Round 11
// 165.170 us; speedup vs baseline: 1.0551x; 1.0551x over previous
//
#include <hip/hip_runtime.h>

#define N_NODES 50000
#define N_EDGES 1600000
#define NB 782            // buckets of 64 dst nodes: ceil(50000/64)
#define NBB 256           // binning blocks
#define CHUNK 6250        // N_EDGES / NBB (exact, even)
#define CAP 2560          // fixed bucket capacity (mean 2046 + 11 sigma)
#define SCAP 3072         // srcp per-bucket capacity (CAP + pad slack)
#define ZROW 50000        // dummy src row (all zeros) for padding
#define NTILES 3125       // 50000 / 16 exact

typedef unsigned short ushort_t;
typedef _Float16 v8h __attribute__((ext_vector_type(8)));
typedef _Float16 v4h __attribute__((ext_vector_type(4)));
typedef float f32x4_t __attribute__((ext_vector_type(4)));

// ========== weight prep: LDS-staged compose + pack + gcur zero ==========
// 8 blocks. Blocks 0-3: z-path (Mz = Wz@Wlz), 4-7: h-path. Block writes
// Bzh ntile (blk&3). Layout (verified r6-r10): Bzh[t]: lane=(t>>3)&63,
// j=t&7, ntile=t>>10, ks=(t>>9)&1; n=ntile*16+(lane&15),
// k=ks*32+((lane>>4)<<3)+j.
__global__ __launch_bounds__(256) void k_wprep2(
    const float* __restrict__ Wz, const float* __restrict__ bz,
    const float* __restrict__ Wlz, const float* __restrict__ blz,
    const float* __restrict__ Wh, const float* __restrict__ bh,
    const float* __restrict__ Wlh, const float* __restrict__ blh,
    const float* __restrict__ Wout,
    float* __restrict__ B2f, _Float16* __restrict__ Bzh,
    _Float16* __restrict__ Bwo, int* __restrict__ gcur) {
  __shared__ float A[64 * 65];    // W (row-major, stride 65: bank-safe)
  __shared__ float Bm[64 * 65];   // Wl
  int tid = threadIdx.x, blk = blockIdx.x;
  bool zpath = blk < 4;
  if (blk == 2) {
    for (int i = tid; i < NB; i += 256) gcur[i] = 0;
  }
  const float* Wsrc = zpath ? Wz : Wh;
  const float* Lsrc = zpath ? Wlz : Wlh;
  for (int idx = tid; idx < 4096; idx += 256) {
    A[(idx >> 6) * 65 + (idx & 63)] = Wsrc[idx];
    Bm[(idx >> 6) * 65 + (idx & 63)] = Lsrc[idx];
  }
  __syncthreads();

  int lane = (tid >> 1) & 63;
  int j0 = (tid & 1) * 4;
  int ks = (tid >> 7) & 1;
  int k0 = ks * 32 + ((lane >> 4) << 3) + j0;
  int col = (blk & 3) * 16 + (lane & 15);
  float a0 = 0.f, a1 = 0.f, a2 = 0.f, a3 = 0.f;
  for (int q = 0; q < 64; ++q) {
    float bv = Bm[q * 65 + col];
    a0 = fmaf(A[k0 * 65 + q], bv, a0);
    a1 = fmaf(A[(k0 + 1) * 65 + q], bv, a1);
    a2 = fmaf(A[(k0 + 2) * 65 + q], bv, a2);
    a3 = fmaf(A[(k0 + 3) * 65 + q], bv, a3);
  }
  int tb = blk * 1024 + tid * 4;
  v4h o; o[0] = (_Float16)a0; o[1] = (_Float16)a1;
  o[2] = (_Float16)a2; o[3] = (_Float16)a3;
  *(v4h*)(Bzh + tb) = o;

  // fused biases: block 0 writes .x (z), block 4 writes .y (h)
  if ((blk == 0 || blk == 4) && tid < 64) {
    float v = zpath ? blz[tid] : blh[tid];
    const float* bb = zpath ? bz : bh;
    for (int q = 0; q < 64; ++q) v = fmaf(bb[q], Bm[q * 65 + tid], v);
    B2f[tid * 2 + (zpath ? 0 : 1)] = v;
  }
  // Bwo pack (plain reformat), block 1
  if (blk == 1) {
    for (int e2 = 0; e2 < 12; ++e2) {
      int t2 = tid * 12 + e2;
      int ln = (t2 >> 3) & 63, j = t2 & 7;
      int ntile = t2 >> 10, ks2 = (t2 >> 9) & 1;
      int n = ntile * 16 + (ln & 15);
      int k = ks2 * 32 + ((ln >> 4) << 3) + j;
      Bwo[t2] = (_Float16)((n < 45) ? Wout[k * 45 + n] : 0.f);
    }
  }
}

// ========== fused binning: one pass over edges, fixed-CAP buckets (r8) =====
__global__ __launch_bounds__(256) void k_bin2(
    const int* __restrict__ ei, int* __restrict__ gcur, int* __restrict__ bins) {
  __shared__ int h[NB];
  __shared__ int segb[NB];
  __shared__ int pk[CHUNK];     // 25 KB
  int tid = threadIdx.x, blk = blockIdx.x;
  for (int i = tid; i < NB; i += 256) h[i] = 0;
  __syncthreads();
  const int2* s2 = (const int2*)(ei + blk * CHUNK);
  const int2* d2 = (const int2*)(ei + N_EDGES + blk * CHUNK);
  for (int i = tid; i < CHUNK / 2; i += 256) {
    int2 s = s2[i];
    int2 d = d2[i];
    pk[2 * i]     = s.x | ((d.x & 63) << 16) | ((d.x >> 6) << 22);
    pk[2 * i + 1] = s.y | ((d.y & 63) << 16) | ((d.y >> 6) << 22);
    atomicAdd(&h[d.x >> 6], 1);
    atomicAdd(&h[d.y >> 6], 1);
  }
  __syncthreads();
  for (int b = tid; b < NB; b += 256) {
    int c = h[b];
    segb[b] = c ? atomicAdd(&gcur[b], c) : 0;
    h[b] = 0;                       // reuse as local cursor
  }
  __syncthreads();
  for (int i = tid; i < CHUNK; i += 256) {
    int v = pk[i];
    int b = (unsigned)v >> 22;
    int p = atomicAdd(&h[b], 1);
    bins[b * CAP + segb[b] + p] = v & 0x3FFFFF;   // src | dl<<16
  }
}

// ---------------- per-bucket sort -> padded per-node CSR + dinv + xp (r8) --
__global__ __launch_bounds__(256, 4) void k_sort(
    const int* __restrict__ bins, const int* __restrict__ gcur,
    const float* __restrict__ x,
    ushort_t* __restrict__ srcp, int2* __restrict__ rowiv,
    float* __restrict__ dinv, _Float16* __restrict__ xp) {
  __shared__ int dg[64], lo[64], cur[64];
  __shared__ float sdin[64];
  __shared__ int Tsh;
  __shared__ ushort_t buf[8192];
  int tid = threadIdx.x, b = blockIdx.x;
  int start = b * CAP, end = start + gcur[b];
  if (tid < 64) dg[tid] = 0;
  __syncthreads();
  for (int i = start + tid; i < end; i += 256)
    atomicAdd(&dg[bins[i] >> 16], 1);
  __syncthreads();
  int pdv = 0;
  if (tid < 64) { pdv = (dg[tid] + 7) & ~7; lo[tid] = pdv; }
  __syncthreads();
  for (int off = 1; off < 64; off <<= 1) {
    int u = 0;
    if (tid < 64 && tid >= off) u = lo[tid - off];
    __syncthreads();
    if (tid < 64) lo[tid] += u;
    __syncthreads();
  }
  int ex = 0;
  if (tid < 64) {
    ex = lo[tid] - pdv;       // exclusive padded offset
    cur[tid] = ex;
    if (tid == 63) Tsh = lo[63];
  }
  __syncthreads();
  int T = Tsh;
  int base = b * SCAP;        // fixed per-bucket srcp region
  for (int i = tid; i < T; i += 256) buf[i] = (ushort_t)ZROW;
  __syncthreads();
  for (int i = start + tid; i < end; i += 256) {
    int v = bins[i];
    int dl = v >> 16;
    int p = atomicAdd(&cur[dl], 1);
    buf[p] = (ushort_t)(v & 0xFFFF);
  }
  __syncthreads();
  for (int i = tid; i < T; i += 256) srcp[base + i] = buf[i];
  if (tid < 64) {
    int v = b * 64 + tid;
    if (v < N_NODES) {
      rowiv[v] = make_int2(base + ex, pdv);
      float dv = rsqrtf((float)dg[tid] + 2.0f);
      dinv[v] = dv;
      sdin[tid] = dv;
    } else {
      sdin[tid] = 0.f;
    }
  }
  __syncthreads();
  int nb64 = b * 4096;  // b*64*64
  for (int idx = tid; idx < 4096; idx += 256) {
    int v = b * 64 + (idx >> 6);
    if (v < N_NODES) xp[nb64 + idx] = (_Float16)(sdin[idx >> 6] * x[nb64 + idx]);
  }
  if (b == 0 && tid < 64) xp[ZROW * 64 + tid] = (_Float16)0.f;
}

// ---------------- gather: 4 edges per wave-load, 4-deep MLP ----------------
// lane = grp(edge slot, lane>>4) x sub(channel quad, lane&15).
__global__ __launch_bounds__(256) void k_agg(
    const ushort_t* __restrict__ srcp, const int2* __restrict__ rowiv,
    const float* __restrict__ dinv, const _Float16* __restrict__ xp,
    _Float16* __restrict__ sxg) {
  int tid = threadIdx.x;
  int lane = tid & 63;
  int grp = lane >> 4;          // edge slot 0..3
  int sub = lane & 15;          // channels sub*4 .. sub*4+3
  int chOff = sub << 2;
  int w = blockIdx.x * 4 + (tid >> 6);
  int nw = gridDim.x * 4;
  for (int v = w; v < N_NODES; v += nw) {
    int vu = __builtin_amdgcn_readfirstlane(v);
    int2 ri = rowiv[vu];
    int beg = ri.x, pd = ri.y;    // pd multiple of 8
    float aA0=0.f,aA1=0.f,aA2=0.f,aA3=0.f, aB0=0.f,aB1=0.f,aB2=0.f,aB3=0.f;
    float aC0=0.f,aC1=0.f,aC2=0.f,aC3=0.f, aD0=0.f,aD1=0.f,aD2=0.f,aD3=0.f;
    for (int e = beg; e < beg + pd; e += 64) {
      int rem = beg + pd - e;
      int m = rem < 64 ? rem : 64;   // multiple of 8
      int sv = (lane < m) ? (int)srcp[e + lane] : ZROW;
      int t = 0;
      for (; t + 16 <= m; t += 16) {   // 16 edges: 4 loads in flight
        int sA = __builtin_amdgcn_ds_bpermute((t + grp) << 2, sv);
        int sB = __builtin_amdgcn_ds_bpermute((t + 4 + grp) << 2, sv);
        int sC = __builtin_amdgcn_ds_bpermute((t + 8 + grp) << 2, sv);
        int sD = __builtin_amdgcn_ds_bpermute((t + 12 + grp) << 2, sv);
        v4h rA = *(const v4h*)(xp + (sA << 6) + chOff);
        v4h rB = *(const v4h*)(xp + (sB << 6) + chOff);
        v4h rC = *(const v4h*)(xp + (sC << 6) + chOff);
        v4h rD = *(const v4h*)(xp + (sD << 6) + chOff);
        aA0 += (float)rA[0]; aA1 += (float)rA[1];
        aA2 += (float)rA[2]; aA3 += (float)rA[3];
        aB0 += (float)rB[0]; aB1 += (float)rB[1];
        aB2 += (float)rB[2]; aB3 += (float)rB[3];
        aC0 += (float)rC[0]; aC1 += (float)rC[1];
        aC2 += (float)rC[2]; aC3 += (float)rC[3];
        aD0 += (float)rD[0]; aD1 += (float)rD[1];
        aD2 += (float)rD[2]; aD3 += (float)rD[3];
      }
      if (t < m) {                    // remaining 8 edges
        int sA = __builtin_amdgcn_ds_bpermute((t + grp) << 2, sv);
        int sB = __builtin_amdgcn_ds_bpermute((t + 4 + grp) << 2, sv);
        v4h rA = *(const v4h*)(xp + (sA << 6) + chOff);
        v4h rB = *(const v4h*)(xp + (sB << 6) + chOff);
        aA0 += (float)rA[0]; aA1 += (float)rA[1];
        aA2 += (float)rA[2]; aA3 += (float)rA[3];
        aB0 += (float)rB[0]; aB1 += (float)rB[1];
        aB2 += (float)rB[2]; aB3 += (float)rB[3];
      }
    }
    float a0 = (aA0 + aB0) + (aC0 + aD0);
    float a1 = (aA1 + aB1) + (aC1 + aD1);
    float a2 = (aA2 + aB2) + (aC2 + aD2);
    float a3 = (aA3 + aB3) + (aC3 + aD3);
    a0 += __shfl_xor(a0, 16); a1 += __shfl_xor(a1, 16);
    a2 += __shfl_xor(a2, 16); a3 += __shfl_xor(a3, 16);
    a0 += __shfl_xor(a0, 32); a1 += __shfl_xor(a1, 32);
    a2 += __shfl_xor(a2, 32); a3 += __shfl_xor(a3, 32);
    if (lane < 16) {
      float dv = dinv[vu];
      v4h self = *(const v4h*)(xp + (vu << 6) + chOff);
      v4h o;
      o[0] = (_Float16)(dv * a0 + 2.f * dv * (float)self[0]);
      o[1] = (_Float16)(dv * a1 + 2.f * dv * (float)self[1]);
      o[2] = (_Float16)(dv * a2 + 2.f * dv * (float)self[2]);
      o[3] = (_Float16)(dv * a3 + 2.f * dv * (float)self[3]);
      *(v4h*)(sxg + (vu << 6) + chOff) = o;
    }
  }
}

// ---------------- MFMA cell + readout (one wave per 16-node tile, r8) ------
__global__ __launch_bounds__(256) void k_cell(
    const _Float16* __restrict__ sxg, const _Float16* __restrict__ Bzh,
    const _Float16* __restrict__ Bwo, const float2* __restrict__ B2,
    const float* __restrict__ bout, float* __restrict__ out) {
  __shared__ __align__(16) _Float16 tbuf[4][16][72];
  int tid = threadIdx.x;
  int lane = tid & 63, wv = tid >> 6;
  int l15 = lane & 15, quad = lane >> 4;
  int tile = blockIdx.x * 4 + wv;
  if (tile >= NTILES) return;    // no barriers in this kernel -> safe

  v8h bzf[8][2], bwf[3][2];
  #pragma unroll
  for (int t = 0; t < 8; ++t)
    #pragma unroll
    for (int ks = 0; ks < 2; ++ks)
      bzf[t][ks] = *(const v8h*)(Bzh + (((t * 2 + ks) * 64 + lane) << 3));
  #pragma unroll
  for (int t = 0; t < 3; ++t)
    #pragma unroll
    for (int ks = 0; ks < 2; ++ks)
      bwf[t][ks] = *(const v8h*)(Bwo + (((t * 2 + ks) * 64 + lane) << 3));
  float zb[4], hb[4], ob[3];
  #pragma unroll
  for (int t = 0; t < 4; ++t) {
    float2 bb = B2[t * 16 + l15];
    zb[t] = bb.x; hb[t] = bb.y;
  }
  #pragma unroll
  for (int t = 0; t < 3; ++t) {
    int c = t * 16 + l15;
    ob[t] = (c < 45) ? bout[c] : 0.f;
  }

  const _Float16* ar = sxg + (tile * 16 + l15) * 64 + quad * 8;
  v8h a0 = *(const v8h*)ar;
  v8h a1 = *(const v8h*)(ar + 32);

  f32x4_t accz[8];
  #pragma unroll
  for (int t = 0; t < 8; ++t) {
    f32x4_t c4 = {0.f, 0.f, 0.f, 0.f};
    c4 = __builtin_amdgcn_mfma_f32_16x16x32_f16(a0, bzf[t][0], c4, 0, 0, 0);
    c4 = __builtin_amdgcn_mfma_f32_16x16x32_f16(a1, bzf[t][1], c4, 0, 0, 0);
    accz[t] = c4;
  }

  #pragma unroll
  for (int t = 0; t < 4; ++t) {
    #pragma unroll
    for (int r = 0; r < 4; ++r) {
      float zv = accz[t][r] + zb[t];
      float hv = accz[t + 4][r] + hb[t];
      float Z = 1.f / (1.f + __expf(-zv));
      float tt = fminf(15.f, fmaxf(-15.f, hv));
      float e2 = __expf(-2.f * tt);
      float Th = (1.f - e2) / (1.f + e2);
      tbuf[wv][quad * 4 + r][t * 16 + l15] = (_Float16)fmaxf((1.f - Z) * Th, 0.f);
    }
  }
  __asm__ volatile("s_waitcnt lgkmcnt(0)" ::: "memory");

  v8h p0 = *(const v8h*)&tbuf[wv][l15][quad * 8];
  v8h p1 = *(const v8h*)&tbuf[wv][l15][32 + quad * 8];

  #pragma unroll
  for (int t = 0; t < 3; ++t) {
    f32x4_t o4 = {0.f, 0.f, 0.f, 0.f};
    o4 = __builtin_amdgcn_mfma_f32_16x16x32_f16(p0, bwf[t][0], o4, 0, 0, 0);
    o4 = __builtin_amdgcn_mfma_f32_16x16x32_f16(p1, bwf[t][1], o4, 0, 0, 0);
    int c = t * 16 + l15;
    if (c < 45) {
      #pragma unroll
      for (int r = 0; r < 4; ++r)
        out[(tile * 16 + quad * 4 + r) * 45 + c] = o4[r] + ob[t];
    }
  }
}

// ---------------- launch ----------------
extern "C" void kernel_launch(void* const* d_in, const int* in_sizes, int n_in,
                              void* d_out, int out_size, void* d_ws, size_t ws_size,
                              hipStream_t stream) {
  const float* x    = (const float*)d_in[0];
  const int*   ei   = (const int*)d_in[1];
  const float* Wz   = (const float*)d_in[2];
  const float* bz   = (const float*)d_in[3];
  const float* Wlz  = (const float*)d_in[4];
  const float* blz  = (const float*)d_in[5];
  // d_in[6..9] (W_r branch) dead: H=0 => H*R=0.
  const float* Wh   = (const float*)d_in[10];
  const float* bh   = (const float*)d_in[11];
  const float* Wlh  = (const float*)d_in[12];
  const float* blh  = (const float*)d_in[13];
  const float* Wout = (const float*)d_in[14];
  const float* bout = (const float*)d_in[15];
  float* out = (float*)d_out;

  char* w = (char*)d_ws;
  // bins (early) and sxg (late) alias: bins dead after k_sort.
  int*      bins  = (int*)(w + 0);            // 782*2560*4 = 8,007,680
  _Float16* sxg   = (_Float16*)(w + 0);       // 6,400,000 (alias)
  int*      gcur  = (int*)(w + 8007680);      // 3,128
  ushort_t* srcp  = (ushort_t*)(w + 8010816); // 782*3072*2 = 4,804,608
  int2*     rowiv = (int2*)(w + 12815424);    // 400,000
  float*    dinv  = (float*)(w + 13215424);   // 200,000
  float2*   B2    = (float2*)(w + 13415424);  // 512
  _Float16* Bzh   = (_Float16*)(w + 13415936);// 16,384
  _Float16* Bwo   = (_Float16*)(w + 13432320);// 6,144
  _Float16* xp    = (_Float16*)(w + 13438464);// 6,400,128 -> ends ~19.8 MB

  k_wprep2<<<8, 256, 0, stream>>>(Wz, bz, Wlz, blz, Wh, bh, Wlh, blh, Wout,
                                  (float*)B2, Bzh, Bwo, gcur);
  k_bin2 <<<NBB, 256, 0, stream>>>(ei, gcur, bins);
  k_sort <<<NB, 256, 0, stream>>>(bins, gcur, x, srcp, rowiv, dinv, xp);
  k_agg  <<<2048, 256, 0, stream>>>(srcp, rowiv, dinv, xp, sxg);
  k_cell <<<NB, 256, 0, stream>>>(sxg, Bzh, Bwo, B2, bout, out);
}

// Round 12
// 164.139 us; speedup vs baseline: 1.0617x; 1.0063x over previous
//
#include <hip/hip_runtime.h>

#define N_NODES 50000
#define N_EDGES 1600000
#define NB 782            // buckets of 64 dst nodes: ceil(50000/64)
#define NBB 256           // binning blocks
#define CHUNK 6250        // N_EDGES / NBB (exact, even)
#define CAP 2560          // fixed bucket capacity (mean 2046 + 11 sigma)
#define SCAP 3072         // srcp per-bucket capacity (CAP + pad slack)
#define ZROW 50000        // dummy src row (all zeros) for padding
#define NTILES 3125       // 50000 / 16 exact

typedef unsigned short ushort_t;
typedef _Float16 v8h __attribute__((ext_vector_type(8)));
typedef _Float16 v4h __attribute__((ext_vector_type(4)));
typedef float f32x4_t __attribute__((ext_vector_type(4)));

// ========== fused binning + weight prep (independent block families) ======
// Blocks 0..255: binning (pack into LDS, reserve segment, scatter).
// Blocks 256..263: weight compose/pack (LDS-staged, stride-65).
// gcur pre-zeroed by hipMemsetAsync. (k_binw body verified correct in r10.)
__global__ __launch_bounds__(256) void k_binw(
    const int* __restrict__ ei, int* __restrict__ gcur, int* __restrict__ bins,
    const float* __restrict__ Wz, const float* __restrict__ bz,
    const float* __restrict__ Wlz, const float* __restrict__ blz,
    const float* __restrict__ Wh, const float* __restrict__ bh,
    const float* __restrict__ Wlh, const float* __restrict__ blh,
    const float* __restrict__ Wout, float* __restrict__ B2f,
    _Float16* __restrict__ Bzh, _Float16* __restrict__ Bwo) {
  __shared__ int arena[8320];   // bin: 2*NB+CHUNK=7814 ints; wprep: 8320 floats
  int tid = threadIdx.x, blk = blockIdx.x;
  if (blk < NBB) {
    int* h    = arena;          // 782
    int* segb = arena + NB;     // 782
    int* pk   = arena + 2 * NB; // 6250
    for (int i = tid; i < NB; i += 256) h[i] = 0;
    __syncthreads();
    const int2* s2 = (const int2*)(ei + blk * CHUNK);
    const int2* d2 = (const int2*)(ei + N_EDGES + blk * CHUNK);
    for (int i = tid; i < CHUNK / 2; i += 256) {
      int2 s = s2[i];
      int2 d = d2[i];
      pk[2 * i]     = s.x | ((d.x & 63) << 16) | ((d.x >> 6) << 22);
      pk[2 * i + 1] = s.y | ((d.y & 63) << 16) | ((d.y >> 6) << 22);
      atomicAdd(&h[d.x >> 6], 1);
      atomicAdd(&h[d.y >> 6], 1);
    }
    __syncthreads();
    for (int b = tid; b < NB; b += 256) {
      int c = h[b];
      segb[b] = c ? atomicAdd(&gcur[b], c) : 0;
      h[b] = 0;                       // reuse as local cursor
    }
    __syncthreads();
    for (int i = tid; i < CHUNK; i += 256) {
      int v = pk[i];
      int b = (unsigned)v >> 22;
      int p = atomicAdd(&h[b], 1);
      bins[b * CAP + segb[b] + p] = v & 0x3FFFFF;   // src | dl<<16
    }
  } else {
    // weight prep: wblk 0-3 z-path, 4-7 h-path; ntile = wblk&3
    // Bzh[t]: lane=(t>>3)&63, j=t&7, ntile=t>>10, ks=(t>>9)&1;
    // n=ntile*16+(lane&15), k=ks*32+((lane>>4)<<3)+j  (verified r6-r11)
    int wblk = blk - NBB;
    float* A  = (float*)arena;           // 64x65
    float* Bm = (float*)(arena + 4160);  // 64x65
    bool zpath = wblk < 4;
    const float* Wsrc = zpath ? Wz : Wh;
    const float* Lsrc = zpath ? Wlz : Wlh;
    for (int idx = tid; idx < 4096; idx += 256) {
      A[(idx >> 6) * 65 + (idx & 63)] = Wsrc[idx];
      Bm[(idx >> 6) * 65 + (idx & 63)] = Lsrc[idx];
    }
    __syncthreads();
    int lane = (tid >> 1) & 63;
    int j0 = (tid & 1) * 4;
    int ks = (tid >> 7) & 1;
    int k0 = ks * 32 + ((lane >> 4) << 3) + j0;
    int col = (wblk & 3) * 16 + (lane & 15);
    float a0 = 0.f, a1 = 0.f, a2 = 0.f, a3 = 0.f;
    for (int q = 0; q < 64; ++q) {
      float bv = Bm[q * 65 + col];
      a0 = fmaf(A[k0 * 65 + q], bv, a0);
      a1 = fmaf(A[(k0 + 1) * 65 + q], bv, a1);
      a2 = fmaf(A[(k0 + 2) * 65 + q], bv, a2);
      a3 = fmaf(A[(k0 + 3) * 65 + q], bv, a3);
    }
    int tb = wblk * 1024 + tid * 4;
    v4h o; o[0] = (_Float16)a0; o[1] = (_Float16)a1;
    o[2] = (_Float16)a2; o[3] = (_Float16)a3;
    *(v4h*)(Bzh + tb) = o;
    if ((wblk == 0 || wblk == 4) && tid < 64) {
      float v = zpath ? blz[tid] : blh[tid];
      const float* bb = zpath ? bz : bh;
      for (int q = 0; q < 64; ++q) v = fmaf(bb[q], Bm[q * 65 + tid], v);
      B2f[tid * 2 + (zpath ? 0 : 1)] = v;
    }
    if (wblk == 1) {
      for (int e2 = 0; e2 < 12; ++e2) {
        int t2 = tid * 12 + e2;
        int ln = (t2 >> 3) & 63, j = t2 & 7;
        int ntile = t2 >> 10, ks2 = (t2 >> 9) & 1;
        int n = ntile * 16 + (ln & 15);
        int k = ks2 * 32 + ((ln >> 4) << 3) + j;
        Bwo[t2] = (_Float16)((n < 45) ? Wout[k * 45 + n] : 0.f);
      }
    }
  }
}

// ---------------- per-bucket sort -> padded per-node CSR + dinv + xp (r8) --
__global__ __launch_bounds__(256, 4) void k_sort(
    const int* __restrict__ bins, const int* __restrict__ gcur,
    const float* __restrict__ x,
    ushort_t* __restrict__ srcp, int2* __restrict__ rowiv,
    float* __restrict__ dinv, _Float16* __restrict__ xp) {
  __shared__ int dg[64], lo[64], cur[64];
  __shared__ float sdin[64];
  __shared__ int Tsh;
  __shared__ ushort_t buf[8192];
  int tid = threadIdx.x, b = blockIdx.x;
  int start = b * CAP, end = start + gcur[b];
  if (tid < 64) dg[tid] = 0;
  __syncthreads();
  for (int i = start + tid; i < end; i += 256)
    atomicAdd(&dg[bins[i] >> 16], 1);
  __syncthreads();
  int pdv = 0;
  if (tid < 64) { pdv = (dg[tid] + 7) & ~7; lo[tid] = pdv; }
  __syncthreads();
  for (int off = 1; off < 64; off <<= 1) {
    int u = 0;
    if (tid < 64 && tid >= off) u = lo[tid - off];
    __syncthreads();
    if (tid < 64) lo[tid] += u;
    __syncthreads();
  }
  int ex = 0;
  if (tid < 64) {
    ex = lo[tid] - pdv;       // exclusive padded offset
    cur[tid] = ex;
    if (tid == 63) Tsh = lo[63];
  }
  __syncthreads();
  int T = Tsh;
  int base = b * SCAP;        // fixed per-bucket srcp region
  for (int i = tid; i < T; i += 256) buf[i] = (ushort_t)ZROW;
  __syncthreads();
  for (int i = start + tid; i < end; i += 256) {
    int v = bins[i];
    int dl = v >> 16;
    int p = atomicAdd(&cur[dl], 1);
    buf[p] = (ushort_t)(v & 0xFFFF);
  }
  __syncthreads();
  for (int i = tid; i < T; i += 256) srcp[base + i] = buf[i];
  if (tid < 64) {
    int v = b * 64 + tid;
    if (v < N_NODES) {
      rowiv[v] = make_int2(base + ex, pdv);
      float dv = rsqrtf((float)dg[tid] + 2.0f);
      dinv[v] = dv;
      sdin[tid] = dv;
    } else {
      sdin[tid] = 0.f;
    }
  }
  __syncthreads();
  int nb64 = b * 4096;  // b*64*64
  for (int idx = tid; idx < 4096; idx += 256) {
    int v = b * 64 + (idx >> 6);
    if (v < N_NODES) xp[nb64 + idx] = (_Float16)(sdin[idx >> 6] * x[nb64 + idx]);
  }
  if (b == 0 && tid < 64) xp[ZROW * 64 + tid] = (_Float16)0.f;
}

// ---------------- gather: 4 edges per wave-load, 4-deep MLP (r11) ----------
__global__ __launch_bounds__(256) void k_agg(
    const ushort_t* __restrict__ srcp, const int2* __restrict__ rowiv,
    const float* __restrict__ dinv, const _Float16* __restrict__ xp,
    _Float16* __restrict__ sxg) {
  int tid = threadIdx.x;
  int lane = tid & 63;
  int grp = lane >> 4;          // edge slot 0..3
  int sub = lane & 15;          // channels sub*4 .. sub*4+3
  int chOff = sub << 2;
  int w = blockIdx.x * 4 + (tid >> 6);
  int nw = gridDim.x * 4;
  for (int v = w; v < N_NODES; v += nw) {
    int vu = __builtin_amdgcn_readfirstlane(v);
    int2 ri = rowiv[vu];
    int beg = ri.x, pd = ri.y;    // pd multiple of 8
    float aA0=0.f,aA1=0.f,aA2=0.f,aA3=0.f, aB0=0.f,aB1=0.f,aB2=0.f,aB3=0.f;
    float aC0=0.f,aC1=0.f,aC2=0.f,aC3=0.f, aD0=0.f,aD1=0.f,aD2=0.f,aD3=0.f;
    for (int e = beg; e < beg + pd; e += 64) {
      int rem = beg + pd - e;
      int m = rem < 64 ? rem : 64;   // multiple of 8
      int sv = (lane < m) ? (int)srcp[e + lane] : ZROW;
      int t = 0;
      for (; t + 16 <= m; t += 16) {   // 16 edges: 4 loads in flight
        int sA = __builtin_amdgcn_ds_bpermute((t + grp) << 2, sv);
        int sB = __builtin_amdgcn_ds_bpermute((t + 4 + grp) << 2, sv);
        int sC = __builtin_amdgcn_ds_bpermute((t + 8 + grp) << 2, sv);
        int sD = __builtin_amdgcn_ds_bpermute((t + 12 + grp) << 2, sv);
        v4h rA = *(const v4h*)(xp + (sA << 6) + chOff);
        v4h rB = *(const v4h*)(xp + (sB << 6) + chOff);
        v4h rC = *(const v4h*)(xp + (sC << 6) + chOff);
        v4h rD = *(const v4h*)(xp + (sD << 6) + chOff);
        aA0 += (float)rA[0]; aA1 += (float)rA[1];
        aA2 += (float)rA[2]; aA3 += (float)rA[3];
        aB0 += (float)rB[0]; aB1 += (float)rB[1];
        aB2 += (float)rB[2]; aB3 += (float)rB[3];
        aC0 += (float)rC[0]; aC1 += (float)rC[1];
        aC2 += (float)rC[2]; aC3 += (float)rC[3];
        aD0 += (float)rD[0]; aD1 += (float)rD[1];
        aD2 += (float)rD[2]; aD3 += (float)rD[3];
      }
      if (t < m) {                    // remaining 8 edges
        int sA = __builtin_amdgcn_ds_bpermute((t + grp) << 2, sv);
        int sB = __builtin_amdgcn_ds_bpermute((t + 4 + grp) << 2, sv);
        v4h rA = *(const v4h*)(xp + (sA << 6) + chOff);
        v4h rB = *(const v4h*)(xp + (sB << 6) + chOff);
        aA0 += (float)rA[0]; aA1 += (float)rA[1];
        aA2 += (float)rA[2]; aA3 += (float)rA[3];
        aB0 += (float)rB[0]; aB1 += (float)rB[1];
        aB2 += (float)rB[2]; aB3 += (float)rB[3];
      }
    }
    float a0 = (aA0 + aB0) + (aC0 + aD0);
    float a1 = (aA1 + aB1) + (aC1 + aD1);
    float a2 = (aA2 + aB2) + (aC2 + aD2);
    float a3 = (aA3 + aB3) + (aC3 + aD3);
    a0 += __shfl_xor(a0, 16); a1 += __shfl_xor(a1, 16);
    a2 += __shfl_xor(a2, 16); a3 += __shfl_xor(a3, 16);
    a0 += __shfl_xor(a0, 32); a1 += __shfl_xor(a1, 32);
    a2 += __shfl_xor(a2, 32); a3 += __shfl_xor(a3, 32);
    if (lane < 16) {
      float dv = dinv[vu];
      v4h self = *(const v4h*)(xp + (vu << 6) + chOff);
      v4h o;
      o[0] = (_Float16)(dv * a0 + 2.f * dv * (float)self[0]);
      o[1] = (_Float16)(dv * a1 + 2.f * dv * (float)self[1]);
      o[2] = (_Float16)(dv * a2 + 2.f * dv * (float)self[2]);
      o[3] = (_Float16)(dv * a3 + 2.f * dv * (float)self[3]);
      *(v4h*)(sxg + (vu << 6) + chOff) = o;
    }
  }
}

// ---------------- MFMA cell + readout (one wave per 16-node tile, r8) ------
__global__ __launch_bounds__(256) void k_cell(
    const _Float16* __restrict__ sxg, const _Float16* __restrict__ Bzh,
    const _Float16* __restrict__ Bwo, const float2* __restrict__ B2,
    const float* __restrict__ bout, float* __restrict__ out) {
  __shared__ __align__(16) _Float16 tbuf[4][16][72];
  int tid = threadIdx.x;
  int lane = tid & 63, wv = tid >> 6;
  int l15 = lane & 15, quad = lane >> 4;
  int tile = blockIdx.x * 4 + wv;
  if (tile >= NTILES) return;    // no barriers in this kernel -> safe

  v8h bzf[8][2], bwf[3][2];
  #pragma unroll
  for (int t = 0; t < 8; ++t)
    #pragma unroll
    for (int ks = 0; ks < 2; ++ks)
      bzf[t][ks] = *(const v8h*)(Bzh + (((t * 2 + ks) * 64 + lane) << 3));
  #pragma unroll
  for (int t = 0; t < 3; ++t)
    #pragma unroll
    for (int ks = 0; ks < 2; ++ks)
      bwf[t][ks] = *(const v8h*)(Bwo + (((t * 2 + ks) * 64 + lane) << 3));
  float zb[4], hb[4], ob[3];
  #pragma unroll
  for (int t = 0; t < 4; ++t) {
    float2 bb = B2[t * 16 + l15];
    zb[t] = bb.x; hb[t] = bb.y;
  }
  #pragma unroll
  for (int t = 0; t < 3; ++t) {
    int c = t * 16 + l15;
    ob[t] = (c < 45) ? bout[c] : 0.f;
  }

  const _Float16* ar = sxg + (tile * 16 + l15) * 64 + quad * 8;
  v8h a0 = *(const v8h*)ar;
  v8h a1 = *(const v8h*)(ar + 32);

  f32x4_t accz[8];
  #pragma unroll
  for (int t = 0; t < 8; ++t) {
    f32x4_t c4 = {0.f, 0.f, 0.f, 0.f};
    c4 = __builtin_amdgcn_mfma_f32_16x16x32_f16(a0, bzf[t][0], c4, 0, 0, 0);
    c4 = __builtin_amdgcn_mfma_f32_16x16x32_f16(a1, bzf[t][1], c4, 0, 0, 0);
    accz[t] = c4;
  }

  #pragma unroll
  for (int t = 0; t < 4; ++t) {
    #pragma unroll
    for (int r = 0; r < 4; ++r) {
      float zv = accz[t][r] + zb[t];
      float hv = accz[t + 4][r] + hb[t];
      float Z = 1.f / (1.f + __expf(-zv));
      float tt = fminf(15.f, fmaxf(-15.f, hv));
      float e2 = __expf(-2.f * tt);
      float Th = (1.f - e2) / (1.f + e2);
      tbuf[wv][quad * 4 + r][t * 16 + l15] = (_Float16)fmaxf((1.f - Z) * Th, 0.f);
    }
  }
  __asm__ volatile("s_waitcnt lgkmcnt(0)" ::: "memory");

  v8h p0 = *(const v8h*)&tbuf[wv][l15][quad * 8];
  v8h p1 = *(const v8h*)&tbuf[wv][l15][32 + quad * 8];

  #pragma unroll
  for (int t = 0; t < 3; ++t) {
    f32x4_t o4 = {0.f, 0.f, 0.f, 0.f};
    o4 = __builtin_amdgcn_mfma_f32_16x16x32_f16(p0, bwf[t][0], o4, 0, 0, 0);
    o4 = __builtin_amdgcn_mfma_f32_16x16x32_f16(p1, bwf[t][1], o4, 0, 0, 0);
    int c = t * 16 + l15;
    if (c < 45) {
      #pragma unroll
      for (int r = 0; r < 4; ++r)
        out[(tile * 16 + quad * 4 + r) * 45 + c] = o4[r] + ob[t];
    }
  }
}

// ---------------- launch ----------------
extern "C" void kernel_launch(void* const* d_in, const int* in_sizes, int n_in,
                              void* d_out, int out_size, void* d_ws, size_t ws_size,
                              hipStream_t stream) {
  const float* x    = (const float*)d_in[0];
  const int*   ei   = (const int*)d_in[1];
  const float* Wz   = (const float*)d_in[2];
  const float* bz   = (const float*)d_in[3];
  const float* Wlz  = (const float*)d_in[4];
  const float* blz  = (const float*)d_in[5];
  // d_in[6..9] (W_r branch) dead: H=0 => H*R=0.
  const float* Wh   = (const float*)d_in[10];
  const float* bh   = (const float*)d_in[11];
  const float* Wlh  = (const float*)d_in[12];
  const float* blh  = (const float*)d_in[13];
  const float* Wout = (const float*)d_in[14];
  const float* bout = (const float*)d_in[15];
  float* out = (float*)d_out;

  char* w = (char*)d_ws;
  // bins (early) and sxg (late) alias: bins dead after k_sort.
  int*      bins  = (int*)(w + 0);            // 782*2560*4 = 8,007,680
  _Float16* sxg   = (_Float16*)(w + 0);       // 6,400,000 (alias)
  int*      gcur  = (int*)(w + 8007680);      // 3,128
  ushort_t* srcp  = (ushort_t*)(w + 8010816); // 782*3072*2 = 4,804,608
  int2*     rowiv = (int2*)(w + 12815424);    // 400,000
  float*    dinv  = (float*)(w + 13215424);   // 200,000
  float2*   B2    = (float2*)(w + 13415424);  // 512
  _Float16* Bzh   = (_Float16*)(w + 13415936);// 16,384
  _Float16* Bwo   = (_Float16*)(w + 13432320);// 6,144
  _Float16* xp    = (_Float16*)(w + 13438464);// 6,400,128 -> ends ~19.8 MB

  hipMemsetAsync(gcur, 0, NB * sizeof(int), stream);
  k_binw <<<NBB + 8, 256, 0, stream>>>(ei, gcur, bins, Wz, bz, Wlz, blz,
                                       Wh, bh, Wlh, blh, Wout,
                                       (float*)B2, Bzh, Bwo);
  k_sort <<<NB, 256, 0, stream>>>(bins, gcur, x, srcp, rowiv, dinv, xp);
  k_agg  <<<2048, 256, 0, stream>>>(srcp, rowiv, dinv, xp, sxg);
  k_cell <<<NB, 256, 0, stream>>>(sxg, Bzh, Bwo, B2, bout, out);
}